// Round 1
// baseline (471.824 us; speedup 1.0000x reference)
//
#include <hip/hip_runtime.h>
#include <cstring>

#define D 128
#define ROW 16512                 // D + D*D
#define DTF (1.0f/4095.0f)
#define HSTEP (64.0f/4095.0f)     // checkpoint block step = 64*dt; also Z scale sigma*dt
#define LDA 132
#define LDB 132

#define XCP_OFF 4096
#define MAT_OFF 12416

// slot map (each slot = 16384 floats = one 128x128 matrix)
#define S_ZP(m)   ((m)-1)                 // Zs^m, m=1..14, Zs = (64*dt)*B
#define S_V(m)    (14+(m))                // V_m = W0*Zs^m, m=0..14
#define S_X(j)    (29+(j))                // X_j = W0*M^(64j), j=0..64
#define S_XZ(m,j) (94 + ((m)-1)*65 + (j)) // X_j*Zs^m, m=1..4
#define S_K2(j)   (354+(j))
#define S_K3(j)   (418+(j))
#define S_PHIT(j) (482+(j))               // transposed block transition
#define S_ZT      546                     // Zs transposed

struct __align__(16) F4 { float v[4]; };

__device__ __forceinline__ float* slotp(float* ws, int k){ return ws + MAT_OFF + (size_t)k*16384; }
__device__ __forceinline__ const float* slotpc(const float* ws, int k){ return ws + MAT_OFF + (size_t)k*16384; }

struct MML { const float* a[14]; const float* b[14]; float* c[14]; };
struct CF  { float cf[64][8]; };          // coeffs of M^i (scaled by 64^-m), m=0..4
struct CXA { int j0; float cx[33][16]; }; // coeffs of M^(64j), m=0..14
struct CY5 { float c[5]; };               // coeffs of M^32, m=0..4

// ---------------- prep: Zs, Zs^T, row0 copy, xcp[0], V0 ----------------
__global__ __launch_bounds__(256) void k_prep(const float* y0, const float* B,
                                              float* ws, float* out) {
  int b = blockIdx.x, t = threadIdx.x;
  if (b < 16) {
    int q = b*256 + t;
    F4 v = ((const F4*)B)[q];
    F4 o;
    #pragma unroll
    for (int e = 0; e < 4; ++e) o.v[e] = HSTEP * v.v[e];
    ((F4*)slotp(ws, S_ZP(1)))[q] = o;
    int r = q >> 5, c0 = (q & 31) << 2;
    float* ZT = slotp(ws, S_ZT);
    #pragma unroll
    for (int e = 0; e < 4; ++e) ZT[(size_t)(c0+e)*128 + r] = o.v[e];
  } else if (b < 32) {
    int q = (b-16)*256 + t;
    ((F4*)out)[q] = ((const F4*)y0)[q];
  } else if (b == 32) {
    if (t < 128) {
      out[16384 + t] = y0[16384 + t];
      ws[XCP_OFF + t] = y0[t];
    }
  } else { // 33..48 : V0 = W0
    int q = (b-33)*256 + t;
    ((F4*)slotp(ws, S_V(0)))[q] = ((const F4*)(y0 + D))[q];
  }
}

// ---------------- generic 16-row-strip matmul pieces ----------------
__device__ __forceinline__ void ldB(const float* Bsrc, float (*Bs)[LDB]) {
  const F4* B4 = (const F4*)Bsrc;
  for (int q = threadIdx.x; q < 4096; q += 256) {
    F4 x = B4[q];
    *(F4*)&Bs[q>>5][(q&31)<<2] = x;
  }
}
__device__ __forceinline__ void ldB_IsX(const float* Bsrc, float scale, float (*Bs)[LDB]) {
  const F4* B4 = (const F4*)Bsrc;
  for (int q = threadIdx.x; q < 4096; q += 256) {
    F4 x = B4[q];
    int row = q >> 5, c0 = (q & 31) << 2;
    F4 o;
    #pragma unroll
    for (int e = 0; e < 4; ++e) o.v[e] = scale * x.v[e];
    int de = row - c0;
    if (de >= 0 && de < 4) o.v[de] += 1.0f;
    *(F4*)&Bs[row][c0] = o;
  }
}
__device__ __forceinline__ void ldA(const float* A, int r0, float (*As)[LDA]) {
  const F4* A4 = (const F4*)(A + (size_t)r0*128);
  for (int q = threadIdx.x; q < 512; q += 256) {
    F4 x = A4[q];
    *(F4*)&As[q>>5][(q&31)<<2] = x;
  }
}
__device__ __forceinline__ void ldA_Y(const float* ws, int j, int r0, const float* cy, float (*As)[LDA]) {
  const F4* s0 = (const F4*)(slotpc(ws,S_X(j))    + (size_t)r0*128);
  const F4* s1 = (const F4*)(slotpc(ws,S_XZ(1,j)) + (size_t)r0*128);
  const F4* s2 = (const F4*)(slotpc(ws,S_XZ(2,j)) + (size_t)r0*128);
  const F4* s3 = (const F4*)(slotpc(ws,S_XZ(3,j)) + (size_t)r0*128);
  const F4* s4 = (const F4*)(slotpc(ws,S_XZ(4,j)) + (size_t)r0*128);
  for (int q = threadIdx.x; q < 512; q += 256) {
    F4 a0 = s0[q], a1 = s1[q], a2 = s2[q], a3 = s3[q], a4 = s4[q];
    F4 o;
    #pragma unroll
    for (int e = 0; e < 4; ++e)
      o.v[e] = cy[0]*a0.v[e] + cy[1]*a1.v[e] + cy[2]*a2.v[e] + cy[3]*a3.v[e] + cy[4]*a4.v[e];
    *(F4*)&As[q>>5][(q&31)<<2] = o;
  }
}
__device__ __forceinline__ void mmc(const float (*As)[LDA], const float (*Bs)[LDB], F4& o0, F4& o1) {
  const int rl = threadIdx.x >> 5, c0 = (threadIdx.x & 31) << 2;
  F4 a0s, a1s;
  #pragma unroll
  for (int e = 0; e < 4; ++e) { a0s.v[e] = 0.f; a1s.v[e] = 0.f; }
  #pragma unroll 8
  for (int k = 0; k < 128; ++k) {
    const F4 bv = *(const F4*)&Bs[k][c0];
    const float a0 = As[rl][k], a1 = As[rl+8][k];
    #pragma unroll
    for (int e = 0; e < 4; ++e) {
      a0s.v[e] = fmaf(a0, bv.v[e], a0s.v[e]);
      a1s.v[e] = fmaf(a1, bv.v[e], a1s.v[e]);
    }
  }
  o0 = a0s; o1 = a1s;
}

__global__ __launch_bounds__(256) void k_mm_list(MML L) {
  __shared__ float As[16][LDA]; __shared__ float Bs[128][LDB];
  int e = blockIdx.x >> 3, r0 = (blockIdx.x & 7) * 16;
  ldA(L.a[e], r0, As); ldB(L.b[e], Bs);
  __syncthreads();
  F4 o0, o1; mmc(As, Bs, o0, o1);
  int rl = threadIdx.x >> 5, c0 = (threadIdx.x & 31) << 2;
  *(F4*)&L.c[e][(size_t)(r0+rl)*128 + c0]   = o0;
  *(F4*)&L.c[e][(size_t)(r0+rl+8)*128 + c0] = o1;
}

// XZ[m][j] = X[j] * Zs^m
__global__ __launch_bounds__(256) void k_xz(float* ws) {
  __shared__ float As[16][LDA]; __shared__ float Bs[128][LDB];
  int e = blockIdx.x >> 3, r0 = (blockIdx.x & 7) * 16;
  int j = e >> 2, m = (e & 3) + 1;
  ldA(slotpc(ws, S_X(j)), r0, As);
  ldB(slotpc(ws, S_ZP(m)), Bs);
  __syncthreads();
  F4 o0, o1; mmc(As, Bs, o0, o1);
  int rl = threadIdx.x >> 5, c0 = (threadIdx.x & 31) << 2;
  float* Cp = slotp(ws, S_XZ(m, j));
  *(F4*)&Cp[(size_t)(r0+rl)*128 + c0]   = o0;
  *(F4*)&Cp[(size_t)(r0+rl+8)*128 + c0] = o1;
}

// X[j] = sum_m cx[j][m] * V[m]
__global__ __launch_bounds__(256) void k_xcomb(float* ws, CXA A) {
  int j = A.j0 + blockIdx.x;
  const float* cx = A.cx[blockIdx.x];
  F4* Xp = (F4*)slotp(ws, S_X(j));
  const F4* Vp[15];
  #pragma unroll
  for (int m = 0; m <= 14; ++m) Vp[m] = (const F4*)slotpc(ws, S_V(m));
  for (int q = threadIdx.x; q < 4096; q += 256) {
    F4 acc;
    #pragma unroll
    for (int e = 0; e < 4; ++e) acc.v[e] = 0.f;
    #pragma unroll
    for (int m = 0; m <= 14; ++m) {
      F4 x = Vp[m][q];
      float c = cx[m];
      #pragma unroll
      for (int e = 0; e < 4; ++e) acc.v[e] = fmaf(c, x.v[e], acc.v[e]);
    }
    Xp[q] = acc;
  }
}

// mode 0: K2 = Y*(I + h/2 X) ; mode 1: K3 = Y*(I + h/2 K2)
__global__ __launch_bounds__(256) void k_fK(float* ws, CY5 cy, int mode) {
  __shared__ float As[16][LDA]; __shared__ float Bs[128][LDB];
  int j = blockIdx.x >> 3, r0 = (blockIdx.x & 7) * 16;
  ldA_Y(ws, j, r0, cy.c, As);
  ldB_IsX(mode ? slotpc(ws, S_K2(j)) : slotpc(ws, S_X(j)), 0.5f*HSTEP, Bs);
  __syncthreads();
  F4 o0, o1; mmc(As, Bs, o0, o1);
  int rl = threadIdx.x >> 5, c0 = (threadIdx.x & 31) << 2;
  float* Cp = mode ? slotp(ws, S_K3(j)) : slotp(ws, S_K2(j));
  *(F4*)&Cp[(size_t)(r0+rl)*128 + c0]   = o0;
  *(F4*)&Cp[(size_t)(r0+rl+8)*128 + c0] = o1;
}

// PhiT[j] = transpose( I + h/6*(X_j + 2K2 + 2K3 + X_{j+1}*(I+h K3)) )
__global__ __launch_bounds__(256) void k_f4(float* ws) {
  __shared__ float As[16][LDA]; __shared__ float Bs[128][LDB];
  int j = blockIdx.x >> 3, r0 = (blockIdx.x & 7) * 16;
  ldA(slotpc(ws, S_X(j+1)), r0, As);
  ldB_IsX(slotpc(ws, S_K3(j)), HSTEP, Bs);
  __syncthreads();
  F4 o0, o1; mmc(As, Bs, o0, o1);
  const int rl = threadIdx.x >> 5, c0 = (threadIdx.x & 31) << 2;
  float* PT = slotp(ws, S_PHIT(j));
  const float h6 = HSTEP / 6.0f;
  const F4* Xj = (const F4*)slotpc(ws, S_X(j));
  const F4* K2 = (const F4*)slotpc(ws, S_K2(j));
  const F4* K3 = (const F4*)slotpc(ws, S_K3(j));
  #pragma unroll
  for (int half = 0; half < 2; ++half) {
    int r = r0 + rl + half*8;
    F4 o = half ? o1 : o0;
    int q = r*32 + (c0 >> 2);
    F4 xj = Xj[q], k2 = K2[q], k3 = K3[q];
    #pragma unroll
    for (int e = 0; e < 4; ++e) {
      float phi = ((r == c0+e) ? 1.0f : 0.0f)
                + h6*(xj.v[e] + 2.0f*k2.v[e] + 2.0f*k3.v[e] + o.v[e]);
      PT[(size_t)(c0+e)*128 + r] = phi;
    }
  }
}

// sequential checkpoint chain: x_{j+1} = Phi_j x_j ; writes x rows n=64(j+1)
__global__ __launch_bounds__(256) void k_xcp(float* ws, float* out) {
  __shared__ float xv[128]; __shared__ float red[128];
  int t = threadIdx.x, r = t & 127, hh = t >> 7;
  if (t < 128) xv[t] = ws[XCP_OFF + t];
  __syncthreads();
  for (int j = 0; j < 63; ++j) {
    const float* PT = slotpc(ws, S_PHIT(j));
    float s = 0.f;
    #pragma unroll 8
    for (int c = hh*64; c < hh*64 + 64; ++c) s = fmaf(PT[(size_t)c*128 + r], xv[c], s);
    if (hh) red[r] = s;
    __syncthreads();
    float nx = 0.f;
    if (!hh) nx = s + red[r];
    __syncthreads();
    if (!hh) {
      xv[r] = nx;
      ws[XCP_OFF + (size_t)(j+1)*128 + r] = nx;
      out[(size_t)(j+1)*64*ROW + r] = nx;
    }
    __syncthreads();
  }
}

// W fill: W_{64j+i} = X_j + sum_{m=1..4} cf[i][m]*XZ_m[j]  (write-bound)
__global__ __launch_bounds__(256) void k_fill(const float* ws, float* out, CF cf) {
  __shared__ float cfs[64][8];
  int t = threadIdx.x;
  for (int q = t; q < 512; q += 256) ((float*)cfs)[q] = ((const float*)cf.cf)[q];
  int j = blockIdx.x >> 4, strip = blockIdx.x & 15;
  int r = strip*8 + (t >> 5);
  int q = r*32 + (t & 31);
  F4 x  = ((const F4*)slotpc(ws, S_X(j)))[q];
  F4 a1 = ((const F4*)slotpc(ws, S_XZ(1,j)))[q];
  F4 a2 = ((const F4*)slotpc(ws, S_XZ(2,j)))[q];
  F4 a3 = ((const F4*)slotpc(ws, S_XZ(3,j)))[q];
  F4 a4 = ((const F4*)slotpc(ws, S_XZ(4,j)))[q];
  __syncthreads();
  for (int i = 0; i < 64; ++i) {
    float c1 = cfs[i][1], c2 = cfs[i][2], c3 = cfs[i][3], c4 = cfs[i][4];
    F4 o;
    #pragma unroll
    for (int e = 0; e < 4; ++e) {
      float v = fmaf(c1, a1.v[e], x.v[e]);
      v = fmaf(c2, a2.v[e], v);
      v = fmaf(c3, a3.v[e], v);
      v = fmaf(c4, a4.v[e], v);
      o.v[e] = v;
    }
    ((F4*)(out + (size_t)(j*64 + i)*ROW + D))[q] = o;
  }
}

// x fill: Heun jumps from checkpoint, rank-2 polynomial trick + one 128x128x64 matmul
__global__ __launch_bounds__(256) void k_phase2(float* ws, float* out, CF cf) {
  __shared__ float XT[128][129];
  __shared__ float uni[128*68];     // U[c][i]
  __shared__ float za[5][128], zb[5][128];
  __shared__ float kv[128], xv[128], red[128];
  __shared__ float cfs[64][8];
  int j = blockIdx.x, t = threadIdx.x;
  {
    const F4* Xg = (const F4*)slotpc(ws, S_X(j));
    for (int q = t; q < 4096; q += 256) {
      F4 x = Xg[q]; int r = q >> 5, c0 = (q & 31) << 2;
      #pragma unroll
      for (int e = 0; e < 4; ++e) XT[c0+e][r] = x.v[e];
    }
    for (int q = t; q < 512; q += 256) ((float*)cfs)[q] = ((const float*)cf.cf)[q];
    if (t < 128) xv[t] = ws[XCP_OFF + (size_t)j*128 + t];
  }
  __syncthreads();
  int r = t & 127, hh = t >> 7;
  { // k1 = X * xv
    float s = 0.f;
    for (int c = hh*64; c < hh*64 + 64; ++c) s = fmaf(XT[c][r], xv[c], s);
    if (hh) red[r] = s;
    __syncthreads();
    if (!hh) kv[r] = s + red[r];
    __syncthreads();
  }
  if (t < 128) { za[0][t] = xv[t]; zb[0][t] = kv[t]; }
  __syncthreads();
  const float* ZTg = slotpc(ws, S_ZT);
  for (int m = 1; m <= 4; ++m) {
    float sa = 0.f, sb = 0.f;
    for (int c = hh*64; c < hh*64 + 64; ++c) {
      float zv = ZTg[(size_t)c*128 + r];
      sa = fmaf(zv, za[m-1][c], sa);
      sb = fmaf(zv, zb[m-1][c], sb);
    }
    if (hh) red[r] = sa;
    __syncthreads();
    if (!hh) za[m][r] = sa + red[r];
    __syncthreads();
    if (hh) red[r] = sb;
    __syncthreads();
    if (!hh) zb[m][r] = sb + red[r];
    __syncthreads();
  }
  // U[c][i] = M^i (xv + h_i k1)
  for (int idx = t; idx < 64*128; idx += 256) {
    int i = idx >> 7, c = idx & 127;
    float val = 0.f;
    if (i >= 1) {
      float hi = i * DTF;
      #pragma unroll
      for (int m = 0; m <= 4; ++m) val = fmaf(cfs[i][m], za[m][c] + hi*zb[m][c], val);
    }
    uni[c*68 + i] = val;
  }
  __syncthreads();
  // k2[r][i] = sum_c X[r][c] U[c][i]
  int rg = t >> 4, i0 = (t & 15) << 2;
  F4 acc[8];
  #pragma unroll
  for (int k = 0; k < 8; ++k)
    #pragma unroll
    for (int e = 0; e < 4; ++e) acc[k].v[e] = 0.f;
  for (int c = 0; c < 128; ++c) {
    F4 b = *(const F4*)&uni[c*68 + i0];
    #pragma unroll
    for (int k = 0; k < 8; ++k) {
      float a = XT[c][rg + 16*k];
      #pragma unroll
      for (int e = 0; e < 4; ++e) acc[k].v[e] = fmaf(a, b.v[e], acc[k].v[e]);
    }
  }
  #pragma unroll
  for (int k = 0; k < 8; ++k) {
    int rr = rg + 16*k;
    float xr = xv[rr], kr = kv[rr];
    #pragma unroll
    for (int e = 0; e < 4; ++e) {
      int i = i0 + e;
      if (i >= 1) {
        float hi = i * DTF;
        out[(size_t)(j*64 + i)*ROW + rr] = xr + 0.5f*hi*(kr + acc[k].v[e]);
      }
    }
  }
}

// ---------------- host ----------------
static void pmul16(const double* a, const double* b, double* o) {
  double r[16];
  for (int i = 0; i < 16; ++i) r[i] = 0.0;
  for (int i = 0; i < 16; ++i) {
    double ai = a[i];
    if (ai == 0.0) continue;
    for (int k = 0; i + k < 16; ++k) r[i+k] += ai*b[k];
  }
  for (int i = 0; i < 16; ++i) o[i] = r[i];
}

extern "C" void kernel_launch(void* const* d_in, const int* in_sizes, int n_in,
                              void* d_out, int out_size, void* d_ws, size_t ws_size,
                              hipStream_t stream) {
  (void)in_sizes; (void)n_in; (void)out_size; (void)ws_size;
  const float* y0 = (const float*)d_in[1];
  const float* Bm = (const float*)d_in[2];
  const float* W0 = y0 + D;
  float* out = (float*)d_out;
  float* ws  = (float*)d_ws;

  // Tsit5 stability polynomial M(z), z = dt*B, via C_s recurrence
  double At[7][7]; memset(At, 0, sizeof(At));
  At[2][1] = 0.161;
  At[3][1] = -0.008480655492356989; At[3][2] = 0.335480655492357;
  At[4][1] = 2.8971530571054935;  At[4][2] = -6.359448489975075;  At[4][3] = 4.3622954328695815;
  At[5][1] = 5.325864828439257;   At[5][2] = -11.748883564062828; At[5][3] = 7.4955393428898365;  At[5][4] = -0.09249506636175525;
  At[6][1] = 5.86145544294642;    At[6][2] = -12.92096931784711;  At[6][3] = 8.159367898576159;   At[6][4] = -0.071584973281401; At[6][5] = -0.028269050394068383;
  const double dB[7] = {0, 0.09646076681806523, 0.01, 0.4798896504144996,
                        1.379008574103742, -3.290069515436081, 2.324710524099774};
  double C[7][16]; memset(C, 0, sizeof(C));
  C[1][0] = 1.0;
  for (int s = 2; s <= 6; ++s) {
    C[s][0] = 1.0;
    for (int k = 1; k < 16; ++k) {
      double acc = 0.0;
      for (int l = 1; l < s; ++l) acc += At[s][l]*C[l][k-1];
      C[s][k] = acc;
    }
  }
  double M[16]; memset(M, 0, sizeof(M)); M[0] = 1.0;
  for (int k = 1; k < 16; ++k) {
    double acc = 0.0;
    for (int s = 1; s <= 6; ++s) acc += dB[s]*C[s][k-1];
    M[k] = acc;
  }
  double p64m[16]; p64m[0] = 1.0;
  for (int m = 1; m < 16; ++m) p64m[m] = p64m[m-1]*64.0;

  CF cfArg; memset(&cfArg, 0, sizeof(cfArg));
  double cur[16]; memset(cur, 0, sizeof(cur)); cur[0] = 1.0;
  for (int i = 0; i < 64; ++i) {
    for (int m = 0; m <= 4; ++m) cfArg.cf[i][m] = (float)(cur[m]/p64m[m]);
    pmul16(cur, M, cur);
  }
  double P64[16]; memcpy(P64, cur, sizeof(P64)); // M^64
  CXA cx0, cx1; memset(&cx0, 0, sizeof(cx0)); memset(&cx1, 0, sizeof(cx1));
  cx0.j0 = 0; cx1.j0 = 33;
  double curX[16]; memset(curX, 0, sizeof(curX)); curX[0] = 1.0;
  for (int j = 0; j <= 64; ++j) {
    float* tgt = (j < 33) ? cx0.cx[j] : cx1.cx[j-33];
    for (int m = 0; m <= 14; ++m) tgt[m] = (float)(curX[m]/p64m[m]);
    pmul16(curX, P64, curX);
  }
  CY5 cy; memset(&cy, 0, sizeof(cy));
  double m32[16]; memset(m32, 0, sizeof(m32)); m32[0] = 1.0;
  for (int r = 0; r < 32; ++r) pmul16(m32, M, m32);
  for (int m = 0; m <= 4; ++m) cy.c[m] = (float)(m32[m]/p64m[m]);

  float* SP[548];
  for (int k = 0; k < 548; ++k) SP[k] = ws + MAT_OFF + (size_t)k*16384;

  k_prep<<<49, 256, 0, stream>>>(y0, Bm, ws, out);

  MML L; memset(&L, 0, sizeof(L));
  // Zs powers: doubling rounds
  L.a[0]=SP[0]; L.b[0]=SP[0]; L.c[0]=SP[1];
  k_mm_list<<<8, 256, 0, stream>>>(L);
  L.a[0]=SP[1]; L.b[0]=SP[0]; L.c[0]=SP[2];
  L.a[1]=SP[1]; L.b[1]=SP[1]; L.c[1]=SP[3];
  k_mm_list<<<16, 256, 0, stream>>>(L);
  for (int q = 0; q < 4; ++q) { L.a[q]=SP[3]; L.b[q]=SP[q]; L.c[q]=SP[4+q]; }
  k_mm_list<<<32, 256, 0, stream>>>(L);
  for (int q = 0; q < 6; ++q) { L.a[q]=SP[7]; L.b[q]=SP[q]; L.c[q]=SP[8+q]; }
  k_mm_list<<<48, 256, 0, stream>>>(L);
  // V_m = W0 * Zs^m
  for (int m = 1; m <= 14; ++m) { L.a[m-1]=W0; L.b[m-1]=SP[m-1]; L.c[m-1]=SP[14+m]; }
  k_mm_list<<<112, 256, 0, stream>>>(L);

  k_xcomb<<<33, 256, 0, stream>>>(ws, cx0);
  k_xcomb<<<32, 256, 0, stream>>>(ws, cx1);
  k_xz<<<2080, 256, 0, stream>>>(ws);
  k_fK<<<512, 256, 0, stream>>>(ws, cy, 0);
  k_fK<<<512, 256, 0, stream>>>(ws, cy, 1);
  k_f4<<<512, 256, 0, stream>>>(ws);
  k_xcp<<<1, 256, 0, stream>>>(ws, out);
  k_fill<<<1024, 256, 0, stream>>>(ws, out, cfArg);
  k_phase2<<<64, 256, 0, stream>>>(ws, out, cfArg);
}

// Round 2
// 393.345 us; speedup vs baseline: 1.1995x; 1.1995x over previous
//
#include <hip/hip_runtime.h>
#include <cstring>

#define D 128
#define ROW 16512                 // D + D*D
#define DTF (1.0f/4095.0f)
#define HSTEP (64.0f/4095.0f)     // checkpoint block step = 64*dt; also Z scale sigma*dt
#define LDA 132
#define LDB 132

#define XCP_OFF 4096
#define MAT_OFF 12416

// slot map (each slot = 16384 floats = one 128x128 matrix)
#define S_ZP(m)   ((m)-1)                 // Zs^m, m=1..8, Zs = (64*dt)*B
#define S_V(m)    (14+(m))                // V_m = W0*Zs^m, m=0..8
#define S_X(j)    (29+(j))                // X_j = W0*M^(64j), j=0..64
#define S_XZ(m,j) (94 + ((m)-1)*65 + (j)) // X_j*Zs^m, m=1..4
#define S_K2(j)   (354+(j))
#define S_K3(j)   (418+(j))
#define S_PA      482                     // scan ping (holds PhiT then prefixes), j=0..62
#define S_ZT      546                     // Zs transposed
#define S_PB      548                     // scan pong, j=0..62

struct __align__(16) F4 { float v[4]; };

__device__ __forceinline__ float* slotp(float* ws, int k){ return ws + MAT_OFF + (size_t)k*16384; }
__device__ __forceinline__ const float* slotpc(const float* ws, int k){ return ws + MAT_OFF + (size_t)k*16384; }

struct MML { const float* a[14]; const float* b[14]; float* c[14]; };
struct CF  { float cf[64][8]; };          // coeffs of M^i (scaled by 64^-m), m=0..4
struct CXA2 { float cx[65][9]; };         // coeffs of M^(64j), m=0..8
struct CY5 { float c[5]; };               // coeffs of M^32, m=0..4

// ---------------- prep: Zs, Zs^T, row0 copy, xcp[0], V0 ----------------
__global__ __launch_bounds__(256) void k_prep(const float* y0, const float* B,
                                              float* ws, float* out) {
  int b = blockIdx.x, t = threadIdx.x;
  if (b < 16) {
    int q = b*256 + t;
    F4 v = ((const F4*)B)[q];
    F4 o;
    #pragma unroll
    for (int e = 0; e < 4; ++e) o.v[e] = HSTEP * v.v[e];
    ((F4*)slotp(ws, S_ZP(1)))[q] = o;
    int r = q >> 5, c0 = (q & 31) << 2;
    float* ZT = slotp(ws, S_ZT);
    #pragma unroll
    for (int e = 0; e < 4; ++e) ZT[(size_t)(c0+e)*128 + r] = o.v[e];
  } else if (b < 32) {
    int q = (b-16)*256 + t;
    ((F4*)out)[q] = ((const F4*)y0)[q];
  } else if (b == 32) {
    if (t < 128) {
      out[16384 + t] = y0[16384 + t];
      ws[XCP_OFF + t] = y0[t];
    }
  } else { // 33..48 : V0 = W0
    int q = (b-33)*256 + t;
    ((F4*)slotp(ws, S_V(0)))[q] = ((const F4*)(y0 + D))[q];
  }
}

// ---------------- generic 16-row-strip matmul pieces ----------------
__device__ __forceinline__ void ldB(const float* Bsrc, float (*Bs)[LDB]) {
  const F4* B4 = (const F4*)Bsrc;
  for (int q = threadIdx.x; q < 4096; q += 256) {
    F4 x = B4[q];
    *(F4*)&Bs[q>>5][(q&31)<<2] = x;
  }
}
__device__ __forceinline__ void ldB_IsX(const float* Bsrc, float scale, float (*Bs)[LDB]) {
  const F4* B4 = (const F4*)Bsrc;
  for (int q = threadIdx.x; q < 4096; q += 256) {
    F4 x = B4[q];
    int row = q >> 5, c0 = (q & 31) << 2;
    F4 o;
    #pragma unroll
    for (int e = 0; e < 4; ++e) o.v[e] = scale * x.v[e];
    int de = row - c0;
    if (de >= 0 && de < 4) o.v[de] += 1.0f;
    *(F4*)&Bs[row][c0] = o;
  }
}
__device__ __forceinline__ void ldA(const float* A, int r0, float (*As)[LDA]) {
  const F4* A4 = (const F4*)(A + (size_t)r0*128);
  for (int q = threadIdx.x; q < 512; q += 256) {
    F4 x = A4[q];
    *(F4*)&As[q>>5][(q&31)<<2] = x;
  }
}
__device__ __forceinline__ void ldA_Y(const float* ws, int j, int r0, const float* cy, float (*As)[LDA]) {
  const F4* s0 = (const F4*)(slotpc(ws,S_X(j))    + (size_t)r0*128);
  const F4* s1 = (const F4*)(slotpc(ws,S_XZ(1,j)) + (size_t)r0*128);
  const F4* s2 = (const F4*)(slotpc(ws,S_XZ(2,j)) + (size_t)r0*128);
  const F4* s3 = (const F4*)(slotpc(ws,S_XZ(3,j)) + (size_t)r0*128);
  const F4* s4 = (const F4*)(slotpc(ws,S_XZ(4,j)) + (size_t)r0*128);
  for (int q = threadIdx.x; q < 512; q += 256) {
    F4 a0 = s0[q], a1 = s1[q], a2 = s2[q], a3 = s3[q], a4 = s4[q];
    F4 o;
    #pragma unroll
    for (int e = 0; e < 4; ++e)
      o.v[e] = cy[0]*a0.v[e] + cy[1]*a1.v[e] + cy[2]*a2.v[e] + cy[3]*a3.v[e] + cy[4]*a4.v[e];
    *(F4*)&As[q>>5][(q&31)<<2] = o;
  }
}
__device__ __forceinline__ void mmc(const float (*As)[LDA], const float (*Bs)[LDB], F4& o0, F4& o1) {
  const int rl = threadIdx.x >> 5, c0 = (threadIdx.x & 31) << 2;
  F4 a0s, a1s;
  #pragma unroll
  for (int e = 0; e < 4; ++e) { a0s.v[e] = 0.f; a1s.v[e] = 0.f; }
  #pragma unroll 8
  for (int k = 0; k < 128; ++k) {
    const F4 bv = *(const F4*)&Bs[k][c0];
    const float a0 = As[rl][k], a1 = As[rl+8][k];
    #pragma unroll
    for (int e = 0; e < 4; ++e) {
      a0s.v[e] = fmaf(a0, bv.v[e], a0s.v[e]);
      a1s.v[e] = fmaf(a1, bv.v[e], a1s.v[e]);
    }
  }
  o0 = a0s; o1 = a1s;
}

__global__ __launch_bounds__(256) void k_mm_list(MML L) {
  __shared__ float As[16][LDA]; __shared__ float Bs[128][LDB];
  int e = blockIdx.x >> 3, r0 = (blockIdx.x & 7) * 16;
  ldA(L.a[e], r0, As); ldB(L.b[e], Bs);
  __syncthreads();
  F4 o0, o1; mmc(As, Bs, o0, o1);
  int rl = threadIdx.x >> 5, c0 = (threadIdx.x & 31) << 2;
  *(F4*)&L.c[e][(size_t)(r0+rl)*128 + c0]   = o0;
  *(F4*)&L.c[e][(size_t)(r0+rl+8)*128 + c0] = o1;
}

// XZ[m][j] = X[j] * Zs^m
__global__ __launch_bounds__(256) void k_xz(float* ws) {
  __shared__ float As[16][LDA]; __shared__ float Bs[128][LDB];
  int e = blockIdx.x >> 3, r0 = (blockIdx.x & 7) * 16;
  int j = e >> 2, m = (e & 3) + 1;
  ldA(slotpc(ws, S_X(j)), r0, As);
  ldB(slotpc(ws, S_ZP(m)), Bs);
  __syncthreads();
  F4 o0, o1; mmc(As, Bs, o0, o1);
  int rl = threadIdx.x >> 5, c0 = (threadIdx.x & 31) << 2;
  float* Cp = slotp(ws, S_XZ(m, j));
  *(F4*)&Cp[(size_t)(r0+rl)*128 + c0]   = o0;
  *(F4*)&Cp[(size_t)(r0+rl+8)*128 + c0] = o1;
}

// X[j] = sum_m cx[j][m] * V[m], m=0..8
__global__ __launch_bounds__(256) void k_xcomb(float* ws, CXA2 A) {
  int j = blockIdx.x;
  const float* cx = A.cx[j];
  F4* Xp = (F4*)slotp(ws, S_X(j));
  const F4* Vp[9];
  #pragma unroll
  for (int m = 0; m <= 8; ++m) Vp[m] = (const F4*)slotpc(ws, S_V(m));
  for (int q = threadIdx.x; q < 4096; q += 256) {
    F4 acc;
    #pragma unroll
    for (int e = 0; e < 4; ++e) acc.v[e] = 0.f;
    #pragma unroll
    for (int m = 0; m <= 8; ++m) {
      F4 x = Vp[m][q];
      float c = cx[m];
      #pragma unroll
      for (int e = 0; e < 4; ++e) acc.v[e] = fmaf(c, x.v[e], acc.v[e]);
    }
    Xp[q] = acc;
  }
}

// mode 0: K2 = Y*(I + h/2 X) ; mode 1: K3 = Y*(I + h/2 K2)
__global__ __launch_bounds__(256) void k_fK(float* ws, CY5 cy, int mode) {
  __shared__ float As[16][LDA]; __shared__ float Bs[128][LDB];
  int j = blockIdx.x >> 3, r0 = (blockIdx.x & 7) * 16;
  ldA_Y(ws, j, r0, cy.c, As);
  ldB_IsX(mode ? slotpc(ws, S_K2(j)) : slotpc(ws, S_X(j)), 0.5f*HSTEP, Bs);
  __syncthreads();
  F4 o0, o1; mmc(As, Bs, o0, o1);
  int rl = threadIdx.x >> 5, c0 = (threadIdx.x & 31) << 2;
  float* Cp = mode ? slotp(ws, S_K3(j)) : slotp(ws, S_K2(j));
  *(F4*)&Cp[(size_t)(r0+rl)*128 + c0]   = o0;
  *(F4*)&Cp[(size_t)(r0+rl+8)*128 + c0] = o1;
}

// PhiT[j] = transpose( I + h/6*(X_j + 2K2 + 2K3 + X_{j+1}*(I+h K3)) ) -> S_PA+j
__global__ __launch_bounds__(256) void k_f4(float* ws) {
  __shared__ float As[16][LDA]; __shared__ float Bs[128][LDB];
  int j = blockIdx.x >> 3, r0 = (blockIdx.x & 7) * 16;
  ldA(slotpc(ws, S_X(j+1)), r0, As);
  ldB_IsX(slotpc(ws, S_K3(j)), HSTEP, Bs);
  __syncthreads();
  F4 o0, o1; mmc(As, Bs, o0, o1);
  const int rl = threadIdx.x >> 5, c0 = (threadIdx.x & 31) << 2;
  float* PT = slotp(ws, S_PA + j);
  const float h6 = HSTEP / 6.0f;
  const F4* Xj = (const F4*)slotpc(ws, S_X(j));
  const F4* K2 = (const F4*)slotpc(ws, S_K2(j));
  const F4* K3 = (const F4*)slotpc(ws, S_K3(j));
  #pragma unroll
  for (int half = 0; half < 2; ++half) {
    int r = r0 + rl + half*8;
    F4 o = half ? o1 : o0;
    int q = r*32 + (c0 >> 2);
    F4 xj = Xj[q], k2 = K2[q], k3 = K3[q];
    #pragma unroll
    for (int e = 0; e < 4; ++e) {
      float phi = ((r == c0+e) ? 1.0f : 0.0f)
                + h6*(xj.v[e] + 2.0f*k2.v[e] + 2.0f*k3.v[e] + o.v[e]);
      PT[(size_t)(c0+e)*128 + r] = phi;
    }
  }
}

// Hillis-Steele inclusive scan round on 63 transposed matrices.
// PT^(2s)_j = PT^(s)_{j-s} * PT^(s)_j  (since (AB)^T = B^T A^T)
__global__ __launch_bounds__(256) void k_scan(float* ws, int shift, int srcBase, int dstBase) {
  __shared__ float As[16][LDA]; __shared__ float Bs[128][LDB];
  int j = blockIdx.x >> 3, strip = blockIdx.x & 7;
  const float* src = slotpc(ws, srcBase + j);
  float* dst = slotp(ws, dstBase + j);
  if (j < shift) { // already final: copy strip
    const F4* s4 = (const F4*)(src + (size_t)strip*16*128);
    F4* d4 = (F4*)(dst + (size_t)strip*16*128);
    for (int q = threadIdx.x; q < 512; q += 256) d4[q] = s4[q];
    return;
  }
  ldA(slotpc(ws, srcBase + j - shift), strip*16, As);
  ldB(src, Bs);
  __syncthreads();
  F4 o0, o1; mmc(As, Bs, o0, o1);
  int rl = threadIdx.x >> 5, c0 = (threadIdx.x & 31) << 2;
  *(F4*)&dst[(size_t)(strip*16+rl)*128 + c0]   = o0;
  *(F4*)&dst[(size_t)(strip*16+rl+8)*128 + c0] = o1;
}

// parallel checkpoint matvecs: x_{j+1} = Psi_j x0 (PsiT in S_PA+j), j=0..62
__global__ __launch_bounds__(256) void k_xcpv(float* ws, float* out) {
  __shared__ float xv[128]; __shared__ float red[128];
  int j = blockIdx.x, t = threadIdx.x, r = t & 127, hh = t >> 7;
  if (t < 128) xv[t] = ws[XCP_OFF + t];
  __syncthreads();
  const float* PT = slotpc(ws, S_PA + j);
  float s = 0.f;
  #pragma unroll 8
  for (int c = hh*64; c < hh*64 + 64; ++c) s = fmaf(PT[(size_t)c*128 + r], xv[c], s);
  if (hh) red[r] = s;
  __syncthreads();
  if (!hh) {
    float nx = s + red[r];
    ws[XCP_OFF + (size_t)(j+1)*128 + r] = nx;
    out[(size_t)(j+1)*64*ROW + r] = nx;
  }
}

// W fill: W_{64j+i} = X_j + sum_{m=1..4} cf[i][m]*XZ_m[j]  (write-bound)
__global__ __launch_bounds__(256) void k_fill(const float* ws, float* out, CF cf) {
  __shared__ float cfs[64][8];
  int t = threadIdx.x;
  for (int q = t; q < 512; q += 256) ((float*)cfs)[q] = ((const float*)cf.cf)[q];
  int j = blockIdx.x >> 4, strip = blockIdx.x & 15;
  int r = strip*8 + (t >> 5);
  int q = r*32 + (t & 31);
  F4 x  = ((const F4*)slotpc(ws, S_X(j)))[q];
  F4 a1 = ((const F4*)slotpc(ws, S_XZ(1,j)))[q];
  F4 a2 = ((const F4*)slotpc(ws, S_XZ(2,j)))[q];
  F4 a3 = ((const F4*)slotpc(ws, S_XZ(3,j)))[q];
  F4 a4 = ((const F4*)slotpc(ws, S_XZ(4,j)))[q];
  __syncthreads();
  for (int i = 0; i < 64; ++i) {
    float c1 = cfs[i][1], c2 = cfs[i][2], c3 = cfs[i][3], c4 = cfs[i][4];
    F4 o;
    #pragma unroll
    for (int e = 0; e < 4; ++e) {
      float v = fmaf(c1, a1.v[e], x.v[e]);
      v = fmaf(c2, a2.v[e], v);
      v = fmaf(c3, a3.v[e], v);
      v = fmaf(c4, a4.v[e], v);
      o.v[e] = v;
    }
    ((F4*)(out + (size_t)(j*64 + i)*ROW + D))[q] = o;
  }
}

// x fill: Heun jumps from checkpoint, rank-2 polynomial trick + one 128x128x64 matmul
__global__ __launch_bounds__(256) void k_phase2(float* ws, float* out, CF cf) {
  __shared__ float XT[128][129];
  __shared__ float uni[128*68];     // U[c][i]
  __shared__ float za[5][128], zb[5][128];
  __shared__ float kv[128], xv[128], red[128];
  __shared__ float cfs[64][8];
  int j = blockIdx.x, t = threadIdx.x;
  {
    const F4* Xg = (const F4*)slotpc(ws, S_X(j));
    for (int q = t; q < 4096; q += 256) {
      F4 x = Xg[q]; int r = q >> 5, c0 = (q & 31) << 2;
      #pragma unroll
      for (int e = 0; e < 4; ++e) XT[c0+e][r] = x.v[e];
    }
    for (int q = t; q < 512; q += 256) ((float*)cfs)[q] = ((const float*)cf.cf)[q];
    if (t < 128) xv[t] = ws[XCP_OFF + (size_t)j*128 + t];
  }
  __syncthreads();
  int r = t & 127, hh = t >> 7;
  { // k1 = X * xv
    float s = 0.f;
    for (int c = hh*64; c < hh*64 + 64; ++c) s = fmaf(XT[c][r], xv[c], s);
    if (hh) red[r] = s;
    __syncthreads();
    if (!hh) kv[r] = s + red[r];
    __syncthreads();
  }
  if (t < 128) { za[0][t] = xv[t]; zb[0][t] = kv[t]; }
  __syncthreads();
  const float* ZTg = slotpc(ws, S_ZT);
  for (int m = 1; m <= 4; ++m) {
    float sa = 0.f, sb = 0.f;
    for (int c = hh*64; c < hh*64 + 64; ++c) {
      float zv = ZTg[(size_t)c*128 + r];
      sa = fmaf(zv, za[m-1][c], sa);
      sb = fmaf(zv, zb[m-1][c], sb);
    }
    if (hh) red[r] = sa;
    __syncthreads();
    if (!hh) za[m][r] = sa + red[r];
    __syncthreads();
    if (hh) red[r] = sb;
    __syncthreads();
    if (!hh) zb[m][r] = sb + red[r];
    __syncthreads();
  }
  // U[c][i] = M^i (xv + h_i k1)
  for (int idx = t; idx < 64*128; idx += 256) {
    int i = idx >> 7, c = idx & 127;
    float val = 0.f;
    if (i >= 1) {
      float hi = i * DTF;
      #pragma unroll
      for (int m = 0; m <= 4; ++m) val = fmaf(cfs[i][m], za[m][c] + hi*zb[m][c], val);
    }
    uni[c*68 + i] = val;
  }
  __syncthreads();
  // k2[r][i] = sum_c X[r][c] U[c][i]
  int rg = t >> 4, i0 = (t & 15) << 2;
  F4 acc[8];
  #pragma unroll
  for (int k = 0; k < 8; ++k)
    #pragma unroll
    for (int e = 0; e < 4; ++e) acc[k].v[e] = 0.f;
  for (int c = 0; c < 128; ++c) {
    F4 b = *(const F4*)&uni[c*68 + i0];
    #pragma unroll
    for (int k = 0; k < 8; ++k) {
      float a = XT[c][rg + 16*k];
      #pragma unroll
      for (int e = 0; e < 4; ++e) acc[k].v[e] = fmaf(a, b.v[e], acc[k].v[e]);
    }
  }
  #pragma unroll
  for (int k = 0; k < 8; ++k) {
    int rr = rg + 16*k;
    float xr = xv[rr], kr = kv[rr];
    #pragma unroll
    for (int e = 0; e < 4; ++e) {
      int i = i0 + e;
      if (i >= 1) {
        float hi = i * DTF;
        out[(size_t)(j*64 + i)*ROW + rr] = xr + 0.5f*hi*(kr + acc[k].v[e]);
      }
    }
  }
}

// ---------------- host ----------------
static void pmul16(const double* a, const double* b, double* o) {
  double r[16];
  for (int i = 0; i < 16; ++i) r[i] = 0.0;
  for (int i = 0; i < 16; ++i) {
    double ai = a[i];
    if (ai == 0.0) continue;
    for (int k = 0; i + k < 16; ++k) r[i+k] += ai*b[k];
  }
  for (int i = 0; i < 16; ++i) o[i] = r[i];
}

extern "C" void kernel_launch(void* const* d_in, const int* in_sizes, int n_in,
                              void* d_out, int out_size, void* d_ws, size_t ws_size,
                              hipStream_t stream) {
  (void)in_sizes; (void)n_in; (void)out_size; (void)ws_size;
  const float* y0 = (const float*)d_in[1];
  const float* Bm = (const float*)d_in[2];
  const float* W0 = y0 + D;
  float* out = (float*)d_out;
  float* ws  = (float*)d_ws;

  // Tsit5 stability polynomial M(z), z = dt*B, via C_s recurrence
  double At[7][7]; memset(At, 0, sizeof(At));
  At[2][1] = 0.161;
  At[3][1] = -0.008480655492356989; At[3][2] = 0.335480655492357;
  At[4][1] = 2.8971530571054935;  At[4][2] = -6.359448489975075;  At[4][3] = 4.3622954328695815;
  At[5][1] = 5.325864828439257;   At[5][2] = -11.748883564062828; At[5][3] = 7.4955393428898365;  At[5][4] = -0.09249506636175525;
  At[6][1] = 5.86145544294642;    At[6][2] = -12.92096931784711;  At[6][3] = 8.159367898576159;   At[6][4] = -0.071584973281401; At[6][5] = -0.028269050394068383;
  const double dB[7] = {0, 0.09646076681806523, 0.01, 0.4798896504144996,
                        1.379008574103742, -3.290069515436081, 2.324710524099774};
  double C[7][16]; memset(C, 0, sizeof(C));
  C[1][0] = 1.0;
  for (int s = 2; s <= 6; ++s) {
    C[s][0] = 1.0;
    for (int k = 1; k < 16; ++k) {
      double acc = 0.0;
      for (int l = 1; l < s; ++l) acc += At[s][l]*C[l][k-1];
      C[s][k] = acc;
    }
  }
  double M[16]; memset(M, 0, sizeof(M)); M[0] = 1.0;
  for (int k = 1; k < 16; ++k) {
    double acc = 0.0;
    for (int s = 1; s <= 6; ++s) acc += dB[s]*C[s][k-1];
    M[k] = acc;
  }
  double p64m[16]; p64m[0] = 1.0;
  for (int m = 1; m < 16; ++m) p64m[m] = p64m[m-1]*64.0;

  CF cfArg; memset(&cfArg, 0, sizeof(cfArg));
  double cur[16]; memset(cur, 0, sizeof(cur)); cur[0] = 1.0;
  for (int i = 0; i < 64; ++i) {
    for (int m = 0; m <= 4; ++m) cfArg.cf[i][m] = (float)(cur[m]/p64m[m]);
    pmul16(cur, M, cur);
  }
  double P64[16]; memcpy(P64, cur, sizeof(P64)); // M^64
  CXA2 cxA; memset(&cxA, 0, sizeof(cxA));
  double curX[16]; memset(curX, 0, sizeof(curX)); curX[0] = 1.0;
  for (int j = 0; j <= 64; ++j) {
    for (int m = 0; m <= 8; ++m) cxA.cx[j][m] = (float)(curX[m]/p64m[m]);
    pmul16(curX, P64, curX);
  }
  CY5 cy; memset(&cy, 0, sizeof(cy));
  double m32[16]; memset(m32, 0, sizeof(m32)); m32[0] = 1.0;
  for (int r = 0; r < 32; ++r) pmul16(m32, M, m32);
  for (int m = 0; m <= 4; ++m) cy.c[m] = (float)(m32[m]/p64m[m]);

  float* SP[611];
  for (int k = 0; k < 611; ++k) SP[k] = ws + MAT_OFF + (size_t)k*16384;

  k_prep<<<49, 256, 0, stream>>>(y0, Bm, ws, out);

  MML L; memset(&L, 0, sizeof(L));
  // Zs powers (need m<=8): Z2; Z3,Z4; Z5..Z8
  L.a[0]=SP[0]; L.b[0]=SP[0]; L.c[0]=SP[1];
  k_mm_list<<<8, 256, 0, stream>>>(L);
  L.a[0]=SP[1]; L.b[0]=SP[0]; L.c[0]=SP[2];
  L.a[1]=SP[1]; L.b[1]=SP[1]; L.c[1]=SP[3];
  k_mm_list<<<16, 256, 0, stream>>>(L);
  for (int q = 0; q < 4; ++q) { L.a[q]=SP[3]; L.b[q]=SP[q]; L.c[q]=SP[4+q]; }
  k_mm_list<<<32, 256, 0, stream>>>(L);
  // V_m = W0 * Zs^m, m=1..8
  for (int m = 1; m <= 8; ++m) { L.a[m-1]=W0; L.b[m-1]=SP[m-1]; L.c[m-1]=SP[14+m]; }
  k_mm_list<<<64, 256, 0, stream>>>(L);

  k_xcomb<<<65, 256, 0, stream>>>(ws, cxA);
  k_xz<<<2080, 256, 0, stream>>>(ws);
  k_fK<<<512, 256, 0, stream>>>(ws, cy, 0);
  k_fK<<<512, 256, 0, stream>>>(ws, cy, 1);
  k_f4<<<512, 256, 0, stream>>>(ws);

  // matrix prefix scan over 63 PhiT, Hillis-Steele, ping-pong PA<->PB
  k_scan<<<504, 256, 0, stream>>>(ws, 1,  S_PA, S_PB);
  k_scan<<<504, 256, 0, stream>>>(ws, 2,  S_PB, S_PA);
  k_scan<<<504, 256, 0, stream>>>(ws, 4,  S_PA, S_PB);
  k_scan<<<504, 256, 0, stream>>>(ws, 8,  S_PB, S_PA);
  k_scan<<<504, 256, 0, stream>>>(ws, 16, S_PA, S_PB);
  k_scan<<<504, 256, 0, stream>>>(ws, 32, S_PB, S_PA);
  k_xcpv<<<63, 256, 0, stream>>>(ws, out);

  k_fill<<<1024, 256, 0, stream>>>(ws, out, cfArg);
  k_phase2<<<64, 256, 0, stream>>>(ws, out, cfArg);
}

// Round 3
// 302.200 us; speedup vs baseline: 1.5613x; 1.3016x over previous
//
#include <hip/hip_runtime.h>
#include <cstring>

#define D 128
#define ROW 16512                 // D + D*D
#define DTF (1.0f/4095.0f)
#define HSTEP (64.0f/4095.0f)     // Zs scale: Zs = (64*dt)*B
#define H4F  (256.0f/4095.0f)     // coarse checkpoint step
#define LDA 132
#define LDB 132

#define XCP_OFF 4096              // 16 x 128 coarse checkpoint vectors
#define MAT_OFF 12416

// slot map (each slot = 16384 floats = one 128x128 matrix)
#define S_ZP(m)   ((m)-1)         // Zs^m, m=1..12
#define S_ZT      12              // Zs transposed
#define S_V(m)    (13+(m))        // V_m = W0*Zs^m, m=0..12
#define S_A(J)    (26+(J))        // W(256J), J=0..15
#define S_BM(J)   (42+(J))        // W(256J+128), J=0..14
#define S_K2(J)   (57+(J))
#define S_K3(J)   (72+(J))
#define S_PA      87              // scan ping, 15 matrices
#define S_PB      102             // scan pong

struct __align__(16) F4 { float v[4]; };

__device__ __forceinline__ float* slotp(float* ws, int k){ return ws + MAT_OFF + (size_t)k*16384; }
__device__ __forceinline__ const float* slotpc(const float* ws, int k){ return ws + MAT_OFF + (size_t)k*16384; }

struct MML { const float* a[14]; const float* b[14]; float* c[14]; };
struct CFX { float cf[64][5]; float cx[64][9]; };  // M^i (deg4) and M^(64j) (deg8), /64^m scaled
struct CMB { float c[31][13]; };                   // rows: A_J (J=0..15), BM_J (J=0..14)
struct CF128 { float cf[128][5]; };                // M^i deg4 for a 128-wide i window

// ---------------- prep: Zs, Zs^T, row0 copy, xcp[0], V0 ----------------
__global__ __launch_bounds__(256) void k_prep(const float* y0, const float* B,
                                              float* ws, float* out) {
  int b = blockIdx.x, t = threadIdx.x;
  if (b < 16) {
    int q = b*256 + t;
    F4 v = ((const F4*)B)[q];
    F4 o;
    #pragma unroll
    for (int e = 0; e < 4; ++e) o.v[e] = HSTEP * v.v[e];
    ((F4*)slotp(ws, S_ZP(1)))[q] = o;
    int r = q >> 5, c0 = (q & 31) << 2;
    float* ZT = slotp(ws, S_ZT);
    #pragma unroll
    for (int e = 0; e < 4; ++e) ZT[(size_t)(c0+e)*128 + r] = o.v[e];
  } else if (b < 32) {
    int q = (b-16)*256 + t;
    ((F4*)out)[q] = ((const F4*)y0)[q];
  } else if (b == 32) {
    if (t < 128) {
      out[16384 + t] = y0[16384 + t];
      ws[XCP_OFF + t] = y0[t];
    }
  } else { // 33..48 : V0 = W0
    int q = (b-33)*256 + t;
    ((F4*)slotp(ws, S_V(0)))[q] = ((const F4*)(y0 + D))[q];
  }
}

// ---------------- generic 16-row-strip matmul pieces ----------------
__device__ __forceinline__ void ldB(const float* Bsrc, float (*Bs)[LDB]) {
  const F4* B4 = (const F4*)Bsrc;
  for (int q = threadIdx.x; q < 4096; q += 256) {
    F4 x = B4[q];
    *(F4*)&Bs[q>>5][(q&31)<<2] = x;
  }
}
__device__ __forceinline__ void ldB_IsX(const float* Bsrc, float scale, float (*Bs)[LDB]) {
  const F4* B4 = (const F4*)Bsrc;
  for (int q = threadIdx.x; q < 4096; q += 256) {
    F4 x = B4[q];
    int row = q >> 5, c0 = (q & 31) << 2;
    F4 o;
    #pragma unroll
    for (int e = 0; e < 4; ++e) o.v[e] = scale * x.v[e];
    int de = row - c0;
    if (de >= 0 && de < 4) o.v[de] += 1.0f;
    *(F4*)&Bs[row][c0] = o;
  }
}
__device__ __forceinline__ void ldA(const float* A, int r0, float (*As)[LDA]) {
  const F4* A4 = (const F4*)(A + (size_t)r0*128);
  for (int q = threadIdx.x; q < 512; q += 256) {
    F4 x = A4[q];
    *(F4*)&As[q>>5][(q&31)<<2] = x;
  }
}
__device__ __forceinline__ void mmc(const float (*As)[LDA], const float (*Bs)[LDB], F4& o0, F4& o1) {
  const int rl = threadIdx.x >> 5, c0 = (threadIdx.x & 31) << 2;
  F4 a0s, a1s;
  #pragma unroll
  for (int e = 0; e < 4; ++e) { a0s.v[e] = 0.f; a1s.v[e] = 0.f; }
  #pragma unroll 8
  for (int k = 0; k < 128; ++k) {
    const F4 bv = *(const F4*)&Bs[k][c0];
    const float a0 = As[rl][k], a1 = As[rl+8][k];
    #pragma unroll
    for (int e = 0; e < 4; ++e) {
      a0s.v[e] = fmaf(a0, bv.v[e], a0s.v[e]);
      a1s.v[e] = fmaf(a1, bv.v[e], a1s.v[e]);
    }
  }
  o0 = a0s; o1 = a1s;
}

__global__ __launch_bounds__(256) void k_mm_list(MML L) {
  __shared__ float As[16][LDA]; __shared__ float Bs[128][LDB];
  int e = blockIdx.x >> 3, r0 = (blockIdx.x & 7) * 16;
  ldA(L.a[e], r0, As); ldB(L.b[e], Bs);
  __syncthreads();
  F4 o0, o1; mmc(As, Bs, o0, o1);
  int rl = threadIdx.x >> 5, c0 = (threadIdx.x & 31) << 2;
  *(F4*)&L.c[e][(size_t)(r0+rl)*128 + c0]   = o0;
  *(F4*)&L.c[e][(size_t)(r0+rl+8)*128 + c0] = o1;
}

// A_J / BM_J = direct 13-term V-combine (rows from host)
__global__ __launch_bounds__(256) void k_comb(float* ws, CMB A) {
  int b = blockIdx.x, t = threadIdx.x;
  int idx = b >> 1, half = b & 1;
  int slot = (idx < 16) ? (S_A(0) + idx) : (S_BM(0) + idx - 16);
  float cr[13];
  #pragma unroll
  for (int m = 0; m < 13; ++m) cr[m] = A.c[idx][m];
  F4* Xp = (F4*)slotp(ws, slot) + half*2048;
  const F4* Vp[13];
  #pragma unroll
  for (int m = 0; m < 13; ++m) Vp[m] = (const F4*)slotpc(ws, S_V(0)+m) + half*2048;
  for (int q = t; q < 2048; q += 256) {
    F4 acc;
    #pragma unroll
    for (int e = 0; e < 4; ++e) acc.v[e] = 0.f;
    #pragma unroll
    for (int m = 0; m < 13; ++m) {
      F4 x = Vp[m][q];
      #pragma unroll
      for (int e = 0; e < 4; ++e) acc.v[e] = fmaf(cr[m], x.v[e], acc.v[e]);
    }
    Xp[q] = acc;
  }
}

// coarse RK4 stage matmuls: mode0: K2 = BM*(I + h/2 A); mode1: K3 = BM*(I + h/2 K2)
__global__ __launch_bounds__(256) void k_fK(float* ws, int mode) {
  __shared__ float As[16][LDA]; __shared__ float Bs[128][LDB];
  int J = blockIdx.x >> 3, r0 = (blockIdx.x & 7) * 16;
  ldA(slotpc(ws, S_BM(J)), r0, As);
  ldB_IsX(mode ? slotpc(ws, S_K2(J)) : slotpc(ws, S_A(J)), 0.5f*H4F, Bs);
  __syncthreads();
  F4 o0, o1; mmc(As, Bs, o0, o1);
  int rl = threadIdx.x >> 5, c0 = (threadIdx.x & 31) << 2;
  float* Cp = mode ? slotp(ws, S_K3(J)) : slotp(ws, S_K2(J));
  *(F4*)&Cp[(size_t)(r0+rl)*128 + c0]   = o0;
  *(F4*)&Cp[(size_t)(r0+rl+8)*128 + c0] = o1;
}

// PhiT[J] = transpose( I + h/6*(A_J + 2K2 + 2K3 + A_{J+1}*(I+h K3)) ) -> S_PA+J
__global__ __launch_bounds__(256) void k_f4(float* ws) {
  __shared__ float As[16][LDA]; __shared__ float Bs[128][LDB];
  int J = blockIdx.x >> 3, r0 = (blockIdx.x & 7) * 16;
  ldA(slotpc(ws, S_A(J+1)), r0, As);
  ldB_IsX(slotpc(ws, S_K3(J)), H4F, Bs);
  __syncthreads();
  F4 o0, o1; mmc(As, Bs, o0, o1);
  const int rl = threadIdx.x >> 5, c0 = (threadIdx.x & 31) << 2;
  float* PT = slotp(ws, S_PA + J);
  const float h6 = H4F / 6.0f;
  const F4* Xj = (const F4*)slotpc(ws, S_A(J));
  const F4* K2 = (const F4*)slotpc(ws, S_K2(J));
  const F4* K3 = (const F4*)slotpc(ws, S_K3(J));
  #pragma unroll
  for (int half = 0; half < 2; ++half) {
    int r = r0 + rl + half*8;
    F4 o = half ? o1 : o0;
    int q = r*32 + (c0 >> 2);
    F4 xj = Xj[q], k2 = K2[q], k3 = K3[q];
    #pragma unroll
    for (int e = 0; e < 4; ++e) {
      float phi = ((r == c0+e) ? 1.0f : 0.0f)
                + h6*(xj.v[e] + 2.0f*k2.v[e] + 2.0f*k3.v[e] + o.v[e]);
      PT[(size_t)(c0+e)*128 + r] = phi;
    }
  }
}

// Hillis-Steele scan round on 15 transposed matrices (PsiT_j = PT_{j-s} * PT_j)
__global__ __launch_bounds__(256) void k_scan(float* ws, int shift, int srcBase, int dstBase) {
  __shared__ float As[16][LDA]; __shared__ float Bs[128][LDB];
  int j = blockIdx.x >> 3, strip = blockIdx.x & 7;
  const float* src = slotpc(ws, srcBase + j);
  float* dst = slotp(ws, dstBase + j);
  if (j < shift) {
    const F4* s4 = (const F4*)(src + (size_t)strip*16*128);
    F4* d4 = (F4*)(dst + (size_t)strip*16*128);
    for (int q = threadIdx.x; q < 512; q += 256) d4[q] = s4[q];
    return;
  }
  ldA(slotpc(ws, srcBase + j - shift), strip*16, As);
  ldB(src, Bs);
  __syncthreads();
  F4 o0, o1; mmc(As, Bs, o0, o1);
  int rl = threadIdx.x >> 5, c0 = (threadIdx.x & 31) << 2;
  *(F4*)&dst[(size_t)(strip*16+rl)*128 + c0]   = o0;
  *(F4*)&dst[(size_t)(strip*16+rl+8)*128 + c0] = o1;
}

// parallel coarse checkpoints: x_{256(K+1)} = Psi_K x0, K=0..14
__global__ __launch_bounds__(256) void k_xcpv(float* ws, float* out) {
  __shared__ float xv[128]; __shared__ float red[128];
  int K = blockIdx.x, t = threadIdx.x, r = t & 127, hh = t >> 7;
  if (t < 128) xv[t] = ws[XCP_OFF + t];
  __syncthreads();
  const float* PT = slotpc(ws, S_PA + K);
  float s = 0.f;
  #pragma unroll 8
  for (int c = hh*64; c < hh*64 + 64; ++c) s = fmaf(PT[(size_t)c*128 + r], xv[c], s);
  if (hh) red[r] = s;
  __syncthreads();
  if (!hh) {
    float nx = s + red[r];
    ws[XCP_OFF + (size_t)(K+1)*128 + r] = nx;
    out[(size_t)(K+1)*256*ROW + r] = nx;
  }
}

// W fill: W_{64j+i} = sum_{p=0..12} conv(cf[i],cx[j])[p] * V_p  (write-bound)
__global__ __launch_bounds__(256) void k_fill(const float* ws, float* out, CFX cc) {
  __shared__ float coefL[64][13];
  int t = threadIdx.x;
  int j = blockIdx.x >> 4, strip = blockIdx.x & 15;
  for (int idx = t; idx < 832; idx += 256) {
    int i = idx / 13, p = idx - i*13;
    float s = 0.f;
    #pragma unroll
    for (int m = 0; m <= 4; ++m) {
      int q = p - m;
      float cxv = (q >= 0 && q <= 8) ? cc.cx[j][q] : 0.f;
      s = fmaf(cc.cf[i][m], cxv, s);
    }
    coefL[i][p] = s;
  }
  int r = strip*8 + (t >> 5);
  int q = r*32 + (t & 31);
  F4 v[13];
  #pragma unroll
  for (int m = 0; m < 13; ++m) v[m] = ((const F4*)slotpc(ws, S_V(0)+m))[q];
  __syncthreads();
  for (int i = 0; i < 64; ++i) {
    F4 o;
    #pragma unroll
    for (int e = 0; e < 4; ++e) o.v[e] = 0.f;
    #pragma unroll
    for (int p = 0; p < 13; ++p) {
      float c = coefL[i][p];
      #pragma unroll
      for (int e = 0; e < 4; ++e) o.v[e] = fmaf(c, v[p].v[e], o.v[e]);
    }
    ((F4*)(out + (size_t)(j*64 + i)*ROW + D))[q] = o;
  }
}

// x fill: Heun jumps from coarse checkpoint; block = (J, half): 64 targets each
__global__ __launch_bounds__(256) void k_phase2(float* ws, float* out, CF128 cc, int ibase) {
  __shared__ float XT[128][129];
  __shared__ float uni[128*68];     // U[c][il]
  __shared__ float za[5][128], zb[5][128];
  __shared__ float kv[128], xv[128], red[128];
  __shared__ float cfs[128][5];
  int b = blockIdx.x, t = threadIdx.x;
  int J = b >> 1, sh = b & 1;
  {
    const F4* Xg = (const F4*)slotpc(ws, S_A(J));
    for (int q = t; q < 4096; q += 256) {
      F4 x = Xg[q]; int r = q >> 5, c0 = (q & 31) << 2;
      #pragma unroll
      for (int e = 0; e < 4; ++e) XT[c0+e][r] = x.v[e];
    }
    for (int q = t; q < 640; q += 256) ((float*)cfs)[q] = ((const float*)cc.cf)[q];
    if (t < 128) xv[t] = ws[XCP_OFF + (size_t)J*128 + t];
  }
  __syncthreads();
  int r = t & 127, hh = t >> 7;
  { // k1 = A_J * xv
    float s = 0.f;
    for (int c = hh*64; c < hh*64 + 64; ++c) s = fmaf(XT[c][r], xv[c], s);
    if (hh) red[r] = s;
    __syncthreads();
    if (!hh) kv[r] = s + red[r];
    __syncthreads();
  }
  if (t < 128) { za[0][t] = xv[t]; zb[0][t] = kv[t]; }
  __syncthreads();
  const float* ZTg = slotpc(ws, S_ZT);
  for (int m = 1; m <= 4; ++m) {
    float sa = 0.f, sb = 0.f;
    for (int c = hh*64; c < hh*64 + 64; ++c) {
      float zv = ZTg[(size_t)c*128 + r];
      sa = fmaf(zv, za[m-1][c], sa);
      sb = fmaf(zv, zb[m-1][c], sb);
    }
    if (hh) red[r] = sa;
    __syncthreads();
    if (!hh) za[m][r] = sa + red[r];
    __syncthreads();
    if (hh) red[r] = sb;
    __syncthreads();
    if (!hh) zb[m][r] = sb + red[r];
    __syncthreads();
  }
  // U[c][il] = M^i (xv + h_i k1), i = ibase + sh*64 + il
  for (int idx = t; idx < 64*128; idx += 256) {
    int il = idx >> 7, c = idx & 127;
    int i = ibase + sh*64 + il;
    float val = 0.f;
    if (i >= 1) {
      float hi = i * DTF;
      int ci = sh*64 + il;
      #pragma unroll
      for (int m = 0; m <= 4; ++m) val = fmaf(cfs[ci][m], za[m][c] + hi*zb[m][c], val);
    }
    uni[c*68 + il] = val;
  }
  __syncthreads();
  // k2[r][il] = sum_c A_J[r][c] U[c][il]
  int rg = t >> 4, i0 = (t & 15) << 2;
  F4 acc[8];
  #pragma unroll
  for (int k = 0; k < 8; ++k)
    #pragma unroll
    for (int e = 0; e < 4; ++e) acc[k].v[e] = 0.f;
  for (int c = 0; c < 128; ++c) {
    F4 bvv = *(const F4*)&uni[c*68 + i0];
    #pragma unroll
    for (int k = 0; k < 8; ++k) {
      float a = XT[c][rg + 16*k];
      #pragma unroll
      for (int e = 0; e < 4; ++e) acc[k].v[e] = fmaf(a, bvv.v[e], acc[k].v[e]);
    }
  }
  #pragma unroll
  for (int k = 0; k < 8; ++k) {
    int rr = rg + 16*k;
    float xr = xv[rr], kr = kv[rr];
    #pragma unroll
    for (int e = 0; e < 4; ++e) {
      int il = i0 + e;
      int i = ibase + sh*64 + il;
      if (i >= 1) {
        float hi = i * DTF;
        out[(size_t)(256*J + i)*ROW + rr] = xr + 0.5f*hi*(kr + acc[k].v[e]);
      }
    }
  }
}

// ---------------- host ----------------
static void pmul16(const double* a, const double* b, double* o) {
  double r[16];
  for (int i = 0; i < 16; ++i) r[i] = 0.0;
  for (int i = 0; i < 16; ++i) {
    double ai = a[i];
    if (ai == 0.0) continue;
    for (int k = 0; i + k < 16; ++k) r[i+k] += ai*b[k];
  }
  for (int i = 0; i < 16; ++i) o[i] = r[i];
}

extern "C" void kernel_launch(void* const* d_in, const int* in_sizes, int n_in,
                              void* d_out, int out_size, void* d_ws, size_t ws_size,
                              hipStream_t stream) {
  (void)in_sizes; (void)n_in; (void)out_size; (void)ws_size;
  const float* y0 = (const float*)d_in[1];
  const float* Bm = (const float*)d_in[2];
  const float* W0 = y0 + D;
  float* out = (float*)d_out;
  float* ws  = (float*)d_ws;

  // Tsit5 stability polynomial M(z), z = dt*B, via C_s recurrence
  double At[7][7]; memset(At, 0, sizeof(At));
  At[2][1] = 0.161;
  At[3][1] = -0.008480655492356989; At[3][2] = 0.335480655492357;
  At[4][1] = 2.8971530571054935;  At[4][2] = -6.359448489975075;  At[4][3] = 4.3622954328695815;
  At[5][1] = 5.325864828439257;   At[5][2] = -11.748883564062828; At[5][3] = 7.4955393428898365;  At[5][4] = -0.09249506636175525;
  At[6][1] = 5.86145544294642;    At[6][2] = -12.92096931784711;  At[6][3] = 8.159367898576159;   At[6][4] = -0.071584973281401; At[6][5] = -0.028269050394068383;
  const double dB[7] = {0, 0.09646076681806523, 0.01, 0.4798896504144996,
                        1.379008574103742, -3.290069515436081, 2.324710524099774};
  double C[7][16]; memset(C, 0, sizeof(C));
  C[1][0] = 1.0;
  for (int s = 2; s <= 6; ++s) {
    C[s][0] = 1.0;
    for (int k = 1; k < 16; ++k) {
      double acc = 0.0;
      for (int l = 1; l < s; ++l) acc += At[s][l]*C[l][k-1];
      C[s][k] = acc;
    }
  }
  double M[16]; memset(M, 0, sizeof(M)); M[0] = 1.0;
  for (int k = 1; k < 16; ++k) {
    double acc = 0.0;
    for (int s = 1; s <= 6; ++s) acc += dB[s]*C[s][k-1];
    M[k] = acc;
  }
  double p64m[16]; p64m[0] = 1.0;
  for (int m = 1; m < 16; ++m) p64m[m] = p64m[m-1]*64.0;

  // harvest scaled coefficient rows of M^n along one pmul chain
  CFX cfx; memset(&cfx, 0, sizeof(cfx));
  CF128 cfP0, cfP1; memset(&cfP0, 0, sizeof(cfP0)); memset(&cfP1, 0, sizeof(cfP1));
  CMB cmb; memset(&cmb, 0, sizeof(cmb));
  double cur[16]; memset(cur, 0, sizeof(cur)); cur[0] = 1.0;
  for (int n = 0; n <= 4032; ++n) {
    if (n < 64)  for (int m = 0; m <= 4; ++m) cfx.cf[n][m] = (float)(cur[m]/p64m[m]);
    if (n < 128) for (int m = 0; m <= 4; ++m) cfP0.cf[n][m] = (float)(cur[m]/p64m[m]);
    else if (n < 256) for (int m = 0; m <= 4; ++m) cfP1.cf[n-128][m] = (float)(cur[m]/p64m[m]);
    if ((n & 63) == 0) {
      int j = n >> 6;
      if (j < 64) for (int m = 0; m <= 8; ++m) cfx.cx[j][m] = (float)(cur[m]/p64m[m]);
    }
    if ((n & 255) == 0) {
      int J = n >> 8;
      if (J <= 15) for (int m = 0; m <= 12; ++m) cmb.c[J][m] = (float)(cur[m]/p64m[m]);
    }
    if ((n & 255) == 128) {
      int J = (n - 128) >> 8;
      if (J <= 14) for (int m = 0; m <= 12; ++m) cmb.c[16+J][m] = (float)(cur[m]/p64m[m]);
    }
    pmul16(cur, M, cur);
  }

  float* SP[117];
  for (int k = 0; k < 117; ++k) SP[k] = ws + MAT_OFF + (size_t)k*16384;

  k_prep<<<49, 256, 0, stream>>>(y0, Bm, ws, out);

  MML L; memset(&L, 0, sizeof(L));
  // Zs powers 2..12 via doubling
  L.a[0]=SP[0]; L.b[0]=SP[0]; L.c[0]=SP[1];                       // Z2
  k_mm_list<<<8, 256, 0, stream>>>(L);
  L.a[0]=SP[1]; L.b[0]=SP[0]; L.c[0]=SP[2];                       // Z3
  L.a[1]=SP[1]; L.b[1]=SP[1]; L.c[1]=SP[3];                       // Z4
  k_mm_list<<<16, 256, 0, stream>>>(L);
  for (int q = 0; q < 4; ++q) { L.a[q]=SP[3]; L.b[q]=SP[q]; L.c[q]=SP[4+q]; }   // Z5..Z8
  k_mm_list<<<32, 256, 0, stream>>>(L);
  for (int q = 0; q < 4; ++q) { L.a[q]=SP[7]; L.b[q]=SP[q]; L.c[q]=SP[8+q]; }   // Z9..Z12
  k_mm_list<<<32, 256, 0, stream>>>(L);
  // V_m = W0 * Zs^m, m=1..12
  for (int m = 1; m <= 12; ++m) { L.a[m-1]=W0; L.b[m-1]=SP[m-1]; L.c[m-1]=SP[13+m]; }
  k_mm_list<<<96, 256, 0, stream>>>(L);

  k_fill<<<1024, 256, 0, stream>>>(ws, out, cfx);      // W path done (needs only V)

  k_comb<<<62, 256, 0, stream>>>(ws, cmb);             // A_J, BM_J
  k_fK<<<120, 256, 0, stream>>>(ws, 0);
  k_fK<<<120, 256, 0, stream>>>(ws, 1);
  k_f4<<<120, 256, 0, stream>>>(ws);

  k_scan<<<120, 256, 0, stream>>>(ws, 1, S_PA, S_PB);
  k_scan<<<120, 256, 0, stream>>>(ws, 2, S_PB, S_PA);
  k_scan<<<120, 256, 0, stream>>>(ws, 4, S_PA, S_PB);
  k_scan<<<120, 256, 0, stream>>>(ws, 8, S_PB, S_PA);
  k_xcpv<<<15, 256, 0, stream>>>(ws, out);

  k_phase2<<<32, 256, 0, stream>>>(ws, out, cfP0, 0);
  k_phase2<<<32, 256, 0, stream>>>(ws, out, cfP1, 128);
}

// Round 4
// 219.074 us; speedup vs baseline: 2.1537x; 1.3794x over previous
//
#include <hip/hip_runtime.h>
#include <cstring>

#define D 128
#define ROW 16512                 // D + D*D
#define DTF (1.0f/4095.0f)
#define HSTEP (64.0f/4095.0f)     // Zs scale: Zs = (64*dt)*B
#define H4F  (256.0f/4095.0f)     // coarse checkpoint step
#define LDA 132
#define LDB 132

#define XCP_OFF 4096              // x0 vector
#define MAT_OFF 12416

// slot map (each slot = 16384 floats = one 128x128 matrix)
#define S_Z1      0               // Zs
#define S_Z2      1
#define S_Z4      2
#define S_ZT      3               // Zs transposed
#define S_V(m)    (4+(m))         // V_m = W0*Zs^m, m=0..6
#define S_A(J)    (11+(J))        // W(256J), J=0..15
#define S_BM(J)   (27+(J))        // W(256J+128), J=0..14
#define S_K2(J)   (42+(J))
#define S_K3(J)   (57+(J))
#define S_PA      72              // scan ping, 15 matrices
#define S_PB      87              // scan pong

struct __align__(16) F4 { float v[4]; };
typedef float f4v __attribute__((ext_vector_type(4)));

__device__ __forceinline__ float* slotp(float* ws, int k){ return ws + MAT_OFF + (size_t)k*16384; }
__device__ __forceinline__ const float* slotpc(const float* ws, int k){ return ws + MAT_OFF + (size_t)k*16384; }

struct MML { const float* a[14]; const float* b[14]; float* c[14]; };
struct CFX { float cf[64][5]; float cx[64][7]; };  // M^i (deg4), M^(64j) (deg6), /64^m scaled
struct CMB { float c[31][7]; };                    // rows: A_J (J=0..15), BM_J (J=0..14)
struct EK  { double e[4][4]; };                    // [z^m](M-1)^k / 64^m, k=1..4, m=1..4

// ---------------- prep: Zs, Zs^T, row0 copy, x0, V0 ----------------
__global__ __launch_bounds__(256) void k_prep(const float* y0, const float* B,
                                              float* ws, float* out) {
  int b = blockIdx.x, t = threadIdx.x;
  if (b < 16) {
    int q = b*256 + t;
    F4 v = ((const F4*)B)[q];
    F4 o;
    #pragma unroll
    for (int e = 0; e < 4; ++e) o.v[e] = HSTEP * v.v[e];
    ((F4*)slotp(ws, S_Z1))[q] = o;
    int r = q >> 5, c0 = (q & 31) << 2;
    float* ZT = slotp(ws, S_ZT);
    #pragma unroll
    for (int e = 0; e < 4; ++e) ZT[(size_t)(c0+e)*128 + r] = o.v[e];
  } else if (b < 32) {
    int q = (b-16)*256 + t;
    ((F4*)out)[q] = ((const F4*)y0)[q];
  } else if (b == 32) {
    if (t < 128) {
      out[16384 + t] = y0[16384 + t];
      ws[XCP_OFF + t] = y0[t];
    }
  } else { // 33..48 : V0 = W0
    int q = (b-33)*256 + t;
    ((F4*)slotp(ws, S_V(0)))[q] = ((const F4*)(y0 + D))[q];
  }
}

// ---------------- generic 16-row-strip matmul pieces ----------------
__device__ __forceinline__ void ldB(const float* Bsrc, float (*Bs)[LDB]) {
  const F4* B4 = (const F4*)Bsrc;
  for (int q = threadIdx.x; q < 4096; q += 256) {
    F4 x = B4[q];
    *(F4*)&Bs[q>>5][(q&31)<<2] = x;
  }
}
__device__ __forceinline__ void ldB_IsX(const float* Bsrc, float scale, float (*Bs)[LDB]) {
  const F4* B4 = (const F4*)Bsrc;
  for (int q = threadIdx.x; q < 4096; q += 256) {
    F4 x = B4[q];
    int row = q >> 5, c0 = (q & 31) << 2;
    F4 o;
    #pragma unroll
    for (int e = 0; e < 4; ++e) o.v[e] = scale * x.v[e];
    int de = row - c0;
    if (de >= 0 && de < 4) o.v[de] += 1.0f;
    *(F4*)&Bs[row][c0] = o;
  }
}
__device__ __forceinline__ void ldA(const float* A, int r0, float (*As)[LDA]) {
  const F4* A4 = (const F4*)(A + (size_t)r0*128);
  for (int q = threadIdx.x; q < 512; q += 256) {
    F4 x = A4[q];
    *(F4*)&As[q>>5][(q&31)<<2] = x;
  }
}
__device__ __forceinline__ void mmc(const float (*As)[LDA], const float (*Bs)[LDB], F4& o0, F4& o1) {
  const int rl = threadIdx.x >> 5, c0 = (threadIdx.x & 31) << 2;
  F4 a0s, a1s;
  #pragma unroll
  for (int e = 0; e < 4; ++e) { a0s.v[e] = 0.f; a1s.v[e] = 0.f; }
  #pragma unroll 8
  for (int k = 0; k < 128; ++k) {
    const F4 bv = *(const F4*)&Bs[k][c0];
    const float a0 = As[rl][k], a1 = As[rl+8][k];
    #pragma unroll
    for (int e = 0; e < 4; ++e) {
      a0s.v[e] = fmaf(a0, bv.v[e], a0s.v[e]);
      a1s.v[e] = fmaf(a1, bv.v[e], a1s.v[e]);
    }
  }
  o0 = a0s; o1 = a1s;
}

__global__ __launch_bounds__(256) void k_mm_list(MML L) {
  __shared__ float As[16][LDA]; __shared__ float Bs[128][LDB];
  int e = blockIdx.x >> 3, r0 = (blockIdx.x & 7) * 16;
  ldA(L.a[e], r0, As); ldB(L.b[e], Bs);
  __syncthreads();
  F4 o0, o1; mmc(As, Bs, o0, o1);
  int rl = threadIdx.x >> 5, c0 = (threadIdx.x & 31) << 2;
  *(F4*)&L.c[e][(size_t)(r0+rl)*128 + c0]   = o0;
  *(F4*)&L.c[e][(size_t)(r0+rl+8)*128 + c0] = o1;
}

// A_J / BM_J = direct 7-term V-combine
__global__ __launch_bounds__(256) void k_comb(float* ws, CMB A) {
  int b = blockIdx.x, t = threadIdx.x;
  int idx = b >> 1, half = b & 1;
  int slot = (idx < 16) ? (S_A(0) + idx) : (S_BM(0) + idx - 16);
  float cr[7];
  #pragma unroll
  for (int m = 0; m < 7; ++m) cr[m] = A.c[idx][m];
  F4* Xp = (F4*)slotp(ws, slot) + half*2048;
  const F4* Vp[7];
  #pragma unroll
  for (int m = 0; m < 7; ++m) Vp[m] = (const F4*)slotpc(ws, S_V(m)) + half*2048;
  for (int q = t; q < 2048; q += 256) {
    F4 acc;
    #pragma unroll
    for (int e = 0; e < 4; ++e) acc.v[e] = 0.f;
    #pragma unroll
    for (int m = 0; m < 7; ++m) {
      F4 x = Vp[m][q];
      #pragma unroll
      for (int e = 0; e < 4; ++e) acc.v[e] = fmaf(cr[m], x.v[e], acc.v[e]);
    }
    Xp[q] = acc;
  }
}

// coarse RK4 stage matmuls: mode0: K2 = BM*(I + h/2 A); mode1: K3 = BM*(I + h/2 K2)
__global__ __launch_bounds__(256) void k_fK(float* ws, int mode) {
  __shared__ float As[16][LDA]; __shared__ float Bs[128][LDB];
  int J = blockIdx.x >> 3, r0 = (blockIdx.x & 7) * 16;
  ldA(slotpc(ws, S_BM(J)), r0, As);
  ldB_IsX(mode ? slotpc(ws, S_K2(J)) : slotpc(ws, S_A(J)), 0.5f*H4F, Bs);
  __syncthreads();
  F4 o0, o1; mmc(As, Bs, o0, o1);
  int rl = threadIdx.x >> 5, c0 = (threadIdx.x & 31) << 2;
  float* Cp = mode ? slotp(ws, S_K3(J)) : slotp(ws, S_K2(J));
  *(F4*)&Cp[(size_t)(r0+rl)*128 + c0]   = o0;
  *(F4*)&Cp[(size_t)(r0+rl+8)*128 + c0] = o1;
}

// PhiT[J] = transpose( I + h/6*(A_J + 2K2 + 2K3 + A_{J+1}*(I+h K3)) ) -> S_PA+J
__global__ __launch_bounds__(256) void k_f4(float* ws) {
  __shared__ float As[16][LDA]; __shared__ float Bs[128][LDB];
  int J = blockIdx.x >> 3, r0 = (blockIdx.x & 7) * 16;
  ldA(slotpc(ws, S_A(J+1)), r0, As);
  ldB_IsX(slotpc(ws, S_K3(J)), H4F, Bs);
  __syncthreads();
  F4 o0, o1; mmc(As, Bs, o0, o1);
  const int rl = threadIdx.x >> 5, c0 = (threadIdx.x & 31) << 2;
  float* PT = slotp(ws, S_PA + J);
  const float h6 = H4F / 6.0f;
  const F4* Xj = (const F4*)slotpc(ws, S_A(J));
  const F4* K2 = (const F4*)slotpc(ws, S_K2(J));
  const F4* K3 = (const F4*)slotpc(ws, S_K3(J));
  #pragma unroll
  for (int half = 0; half < 2; ++half) {
    int r = r0 + rl + half*8;
    F4 o = half ? o1 : o0;
    int q = r*32 + (c0 >> 2);
    F4 xj = Xj[q], k2 = K2[q], k3 = K3[q];
    #pragma unroll
    for (int e = 0; e < 4; ++e) {
      float phi = ((r == c0+e) ? 1.0f : 0.0f)
                + h6*(xj.v[e] + 2.0f*k2.v[e] + 2.0f*k3.v[e] + o.v[e]);
      PT[(size_t)(c0+e)*128 + r] = phi;
    }
  }
}

// Hillis-Steele scan round on 15 transposed matrices (PsiT_j = PT_{j-s} * PT_j)
__global__ __launch_bounds__(256) void k_scan(float* ws, int shift, int srcBase, int dstBase) {
  __shared__ float As[16][LDA]; __shared__ float Bs[128][LDB];
  int j = blockIdx.x >> 3, strip = blockIdx.x & 7;
  const float* src = slotpc(ws, srcBase + j);
  float* dst = slotp(ws, dstBase + j);
  if (j < shift) {
    const F4* s4 = (const F4*)(src + (size_t)strip*16*128);
    F4* d4 = (F4*)(dst + (size_t)strip*16*128);
    for (int q = threadIdx.x; q < 512; q += 256) d4[q] = s4[q];
    return;
  }
  ldA(slotpc(ws, srcBase + j - shift), strip*16, As);
  ldB(src, Bs);
  __syncthreads();
  F4 o0, o1; mmc(As, Bs, o0, o1);
  int rl = threadIdx.x >> 5, c0 = (threadIdx.x & 31) << 2;
  *(F4*)&dst[(size_t)(strip*16+rl)*128 + c0]   = o0;
  *(F4*)&dst[(size_t)(strip*16+rl+8)*128 + c0] = o1;
}

// W fill: W_{64j+i} = sum_{p=0..6} conv(cf[i],cx[j])[p] * V_p  (write-bound)
__global__ __launch_bounds__(256) void k_fill(const float* ws, float* out, CFX cc) {
  __shared__ float coefL[64][7];
  int t = threadIdx.x;
  int j = blockIdx.x >> 4, strip = blockIdx.x & 15;
  for (int idx = t; idx < 448; idx += 256) {
    int i = idx / 7, p = idx - i*7;
    float s = 0.f;
    #pragma unroll
    for (int m = 0; m <= 4; ++m) {
      int q = p - m;
      float cxv = (q >= 0) ? cc.cx[j][q] : 0.f;
      s = fmaf(cc.cf[i][m], cxv, s);
    }
    coefL[i][p] = s;
  }
  int r = strip*8 + (t >> 5);
  int q = r*32 + (t & 31);
  F4 v[7];
  #pragma unroll
  for (int m = 0; m < 7; ++m) v[m] = ((const F4*)slotpc(ws, S_V(m)))[q];
  __syncthreads();
  for (int i = 0; i < 64; ++i) {
    f4v o = {0.f, 0.f, 0.f, 0.f};
    #pragma unroll
    for (int p = 0; p < 7; ++p) {
      float c = coefL[i][p];
      #pragma unroll
      for (int e = 0; e < 4; ++e) o[e] = fmaf(c, v[p].v[e], o[e]);
    }
    __builtin_nontemporal_store(o, (f4v*)(out + (size_t)(j*64 + i)*ROW + D + q*4));
  }
}

// x fill: per block (J, w): checkpoint matvec + Heun jumps for i = w*64 + il
__global__ __launch_bounds__(256) void k_phase2(float* ws, float* out, EK ek) {
  __shared__ float XT[128][129];
  __shared__ float uni[128*68];     // U[c][il]
  __shared__ float za[5][128], zb[5][128];
  __shared__ float kv[128], xv[128], red[128], xs0[128];
  __shared__ float cfs[64][5];
  int b = blockIdx.x, t = threadIdx.x;
  int J = b >> 2, w = b & 3;
  {
    const F4* Xg = (const F4*)slotpc(ws, S_A(J));
    for (int q = t; q < 4096; q += 256) {
      F4 x = Xg[q]; int r = q >> 5, c0 = (q & 31) << 2;
      #pragma unroll
      for (int e = 0; e < 4; ++e) XT[c0+e][r] = x.v[e];
    }
    if (t < 64) { // cfs[il][m] = [Zs^m] M^(w*64+il), closed form via binomials
      double di = (double)(w*64 + t);
      double b1 = di, b2 = b1*(di-1.0)*0.5, b3 = b2*(di-2.0)*(1.0/3.0), b4 = b3*(di-3.0)*0.25;
      cfs[t][0] = 1.f;
      cfs[t][1] = (float)(b1*ek.e[0][0]);
      cfs[t][2] = (float)(b1*ek.e[0][1] + b2*ek.e[1][1]);
      cfs[t][3] = (float)(b1*ek.e[0][2] + b2*ek.e[1][2] + b3*ek.e[2][2]);
      cfs[t][4] = (float)(b1*ek.e[0][3] + b2*ek.e[1][3] + b3*ek.e[2][3] + b4*ek.e[3][3]);
    }
    if (t < 128) xs0[t] = ws[XCP_OFF + t];
  }
  __syncthreads();
  int r = t & 127, hh = t >> 7;
  if (J > 0) { // xv = Psi_{J-1} x0
    const float* PT = slotpc(ws, S_PA + J - 1);
    float s = 0.f;
    #pragma unroll 8
    for (int c = hh*64; c < hh*64 + 64; ++c) s = fmaf(PT[(size_t)c*128 + r], xs0[c], s);
    if (hh) red[r] = s;
    __syncthreads();
    if (!hh) {
      float nx = s + red[r];
      xv[r] = nx;
      if (w == 0) out[(size_t)(256*J)*ROW + r] = nx;
    }
  } else if (t < 128) {
    xv[t] = xs0[t];
  }
  __syncthreads();
  { // k1 = A_J * xv
    float s = 0.f;
    for (int c = hh*64; c < hh*64 + 64; ++c) s = fmaf(XT[c][r], xv[c], s);
    if (hh) red[r] = s;
    __syncthreads();
    if (!hh) kv[r] = s + red[r];
    __syncthreads();
  }
  if (t < 128) { za[0][t] = xv[t]; zb[0][t] = kv[t]; }
  __syncthreads();
  const float* ZTg = slotpc(ws, S_ZT);
  for (int m = 1; m <= 4; ++m) {
    float sa = 0.f, sb = 0.f;
    for (int c = hh*64; c < hh*64 + 64; ++c) {
      float zv = ZTg[(size_t)c*128 + r];
      sa = fmaf(zv, za[m-1][c], sa);
      sb = fmaf(zv, zb[m-1][c], sb);
    }
    if (hh) red[r] = sa;
    __syncthreads();
    if (!hh) za[m][r] = sa + red[r];
    __syncthreads();
    if (hh) red[r] = sb;
    __syncthreads();
    if (!hh) zb[m][r] = sb + red[r];
    __syncthreads();
  }
  // U[c][il] = M^i (xv + h_i k1), i = w*64 + il
  for (int idx = t; idx < 64*128; idx += 256) {
    int il = idx >> 7, c = idx & 127;
    int i = w*64 + il;
    float val = 0.f;
    if (i >= 1) {
      float hi = i * DTF;
      #pragma unroll
      for (int m = 0; m <= 4; ++m) val = fmaf(cfs[il][m], za[m][c] + hi*zb[m][c], val);
    }
    uni[c*68 + il] = val;
  }
  __syncthreads();
  // k2[r][il] = sum_c A_J[r][c] U[c][il]
  int rg = t >> 4, i0 = (t & 15) << 2;
  F4 acc[8];
  #pragma unroll
  for (int k = 0; k < 8; ++k)
    #pragma unroll
    for (int e = 0; e < 4; ++e) acc[k].v[e] = 0.f;
  for (int c = 0; c < 128; ++c) {
    F4 bvv = *(const F4*)&uni[c*68 + i0];
    #pragma unroll
    for (int k = 0; k < 8; ++k) {
      float a = XT[c][rg + 16*k];
      #pragma unroll
      for (int e = 0; e < 4; ++e) acc[k].v[e] = fmaf(a, bvv.v[e], acc[k].v[e]);
    }
  }
  #pragma unroll
  for (int k = 0; k < 8; ++k) {
    int rr = rg + 16*k;
    float xr = xv[rr], kr = kv[rr];
    #pragma unroll
    for (int e = 0; e < 4; ++e) {
      int il = i0 + e;
      int i = w*64 + il;
      if (i >= 1) {
        float hi = i * DTF;
        out[(size_t)(256*J + i)*ROW + rr] = xr + 0.5f*hi*(kr + acc[k].v[e]);
      }
    }
  }
}

// ---------------- host ----------------
static void pmul16(const double* a, const double* b, double* o) {
  double r[16];
  for (int i = 0; i < 16; ++i) r[i] = 0.0;
  for (int i = 0; i < 16; ++i) {
    double ai = a[i];
    if (ai == 0.0) continue;
    for (int k = 0; i + k < 16; ++k) r[i+k] += ai*b[k];
  }
  for (int i = 0; i < 16; ++i) o[i] = r[i];
}

extern "C" void kernel_launch(void* const* d_in, const int* in_sizes, int n_in,
                              void* d_out, int out_size, void* d_ws, size_t ws_size,
                              hipStream_t stream) {
  (void)in_sizes; (void)n_in; (void)out_size; (void)ws_size;
  const float* y0 = (const float*)d_in[1];
  const float* Bm = (const float*)d_in[2];
  const float* W0 = y0 + D;
  float* out = (float*)d_out;
  float* ws  = (float*)d_ws;

  // Tsit5 stability polynomial M(z), z = dt*B, via C_s recurrence
  double At[7][7]; memset(At, 0, sizeof(At));
  At[2][1] = 0.161;
  At[3][1] = -0.008480655492356989; At[3][2] = 0.335480655492357;
  At[4][1] = 2.8971530571054935;  At[4][2] = -6.359448489975075;  At[4][3] = 4.3622954328695815;
  At[5][1] = 5.325864828439257;   At[5][2] = -11.748883564062828; At[5][3] = 7.4955393428898365;  At[5][4] = -0.09249506636175525;
  At[6][1] = 5.86145544294642;    At[6][2] = -12.92096931784711;  At[6][3] = 8.159367898576159;   At[6][4] = -0.071584973281401; At[6][5] = -0.028269050394068383;
  const double dB[7] = {0, 0.09646076681806523, 0.01, 0.4798896504144996,
                        1.379008574103742, -3.290069515436081, 2.324710524099774};
  double C[7][16]; memset(C, 0, sizeof(C));
  C[1][0] = 1.0;
  for (int s = 2; s <= 6; ++s) {
    C[s][0] = 1.0;
    for (int k = 1; k < 16; ++k) {
      double acc = 0.0;
      for (int l = 1; l < s; ++l) acc += At[s][l]*C[l][k-1];
      C[s][k] = acc;
    }
  }
  double M[16]; memset(M, 0, sizeof(M)); M[0] = 1.0;
  for (int k = 1; k < 16; ++k) {
    double acc = 0.0;
    for (int s = 1; s <= 6; ++s) acc += dB[s]*C[s][k-1];
    M[k] = acc;
  }
  double p64m[16]; p64m[0] = 1.0;
  for (int m = 1; m < 16; ++m) p64m[m] = p64m[m-1]*64.0;

  // harvest scaled coefficient rows of M^n along one pmul chain
  CFX cfx; memset(&cfx, 0, sizeof(cfx));
  CMB cmb; memset(&cmb, 0, sizeof(cmb));
  double cur[16]; memset(cur, 0, sizeof(cur)); cur[0] = 1.0;
  for (int n = 0; n <= 4032; ++n) {
    if (n < 64)  for (int m = 0; m <= 4; ++m) cfx.cf[n][m] = (float)(cur[m]/p64m[m]);
    if ((n & 63) == 0) {
      int j = n >> 6;
      if (j < 64) for (int m = 0; m <= 6; ++m) cfx.cx[j][m] = (float)(cur[m]/p64m[m]);
    }
    if ((n & 255) == 0) {
      int J = n >> 8;
      if (J <= 15) for (int m = 0; m <= 6; ++m) cmb.c[J][m] = (float)(cur[m]/p64m[m]);
    }
    if ((n & 255) == 128) {
      int J = (n - 128) >> 8;
      if (J <= 14) for (int m = 0; m <= 6; ++m) cmb.c[16+J][m] = (float)(cur[m]/p64m[m]);
    }
    pmul16(cur, M, cur);
  }

  // EK: [z^m](M-1)^k / 64^m for phase2's closed-form M^i coefficients
  EK ek; memset(&ek, 0, sizeof(ek));
  {
    double e1[5] = {0,0,0,0,0}, e2[5] = {0,0,0,0,0}, e3[5] = {0,0,0,0,0}, e4[5] = {0,0,0,0,0};
    for (int m = 1; m <= 4; ++m) e1[m] = M[m];
    for (int m = 2; m <= 4; ++m) for (int a = 1; a < m; ++a) e2[m] += e1[a]*e1[m-a];
    for (int m = 3; m <= 4; ++m) for (int a = 2; a < m; ++a) e3[m] += e2[a]*e1[m-a];
    e4[4] = e3[3]*e1[1];
    for (int m = 1; m <= 4; ++m) {
      ek.e[0][m-1] = e1[m]/p64m[m];
      ek.e[1][m-1] = e2[m]/p64m[m];
      ek.e[2][m-1] = e3[m]/p64m[m];
      ek.e[3][m-1] = e4[m]/p64m[m];
    }
  }

  float* SP = ws + MAT_OFF;
  auto sp = [&](int k){ return SP + (size_t)k*16384; };

  k_prep<<<49, 256, 0, stream>>>(y0, Bm, ws, out);

  MML L; memset(&L, 0, sizeof(L));
  // round A: Z2 = Zs*Zs ; V1 = W0*Zs
  L.a[0]=sp(S_Z1); L.b[0]=sp(S_Z1); L.c[0]=sp(S_Z2);
  L.a[1]=W0;       L.b[1]=sp(S_Z1); L.c[1]=sp(S_V(1));
  k_mm_list<<<16, 256, 0, stream>>>(L);
  // round B: Z4 = Z2*Z2 ; V2 = W0*Z2 ; V3 = V1*Z2
  L.a[0]=sp(S_Z2);   L.b[0]=sp(S_Z2); L.c[0]=sp(S_Z4);
  L.a[1]=W0;         L.b[1]=sp(S_Z2); L.c[1]=sp(S_V(2));
  L.a[2]=sp(S_V(1)); L.b[2]=sp(S_Z2); L.c[2]=sp(S_V(3));
  k_mm_list<<<24, 256, 0, stream>>>(L);
  // round C: V4 = V2*Z2 ; V5 = V3*Z2 ; V6 = V2*Z4
  L.a[0]=sp(S_V(2)); L.b[0]=sp(S_Z2); L.c[0]=sp(S_V(4));
  L.a[1]=sp(S_V(3)); L.b[1]=sp(S_Z2); L.c[1]=sp(S_V(5));
  L.a[2]=sp(S_V(2)); L.b[2]=sp(S_Z4); L.c[2]=sp(S_V(6));
  k_mm_list<<<24, 256, 0, stream>>>(L);

  k_comb<<<62, 256, 0, stream>>>(ws, cmb);             // A_J, BM_J
  k_fK<<<120, 256, 0, stream>>>(ws, 0);
  k_fK<<<120, 256, 0, stream>>>(ws, 1);
  k_f4<<<120, 256, 0, stream>>>(ws);

  k_scan<<<120, 256, 0, stream>>>(ws, 1, S_PA, S_PB);
  k_scan<<<120, 256, 0, stream>>>(ws, 2, S_PB, S_PA);
  k_scan<<<120, 256, 0, stream>>>(ws, 4, S_PA, S_PB);
  k_scan<<<120, 256, 0, stream>>>(ws, 8, S_PB, S_PA);

  k_phase2<<<64, 256, 0, stream>>>(ws, out, ek);
  k_fill<<<1024, 256, 0, stream>>>(ws, out, cfx);
}